// Round 9
// baseline (72.498 us; speedup 1.0000x reference)
//
#include <hip/hip_runtime.h>

#define BB 8
#define TT 128
#define DD 256
#define LOG2E 1.44269504088896340736f

// Phase 1: one block per (b,t), 512 threads = (q, half h). Thread (q,h)
// computes HALF of both sums over k in [128h, 128h+128):
//   colsum_h[q] = sum_{p in half} exp(dec[p]*enc[t,q])
//   rowsum_h[q] = sum_{r in half} exp(dec[q]*enc[t,r])
// -> 256 exps/thread, 8192 waves total = 8 waves/SIMD (vs R8's 4): doubles
// latency hiding on the s_load->mul->exp chains while keeping the same
// trans-pipe demand (134M exps, ~6.8us floor). Halves combine via one tiny
// LDS exchange (conflict-free: consecutive lanes). No register arrays ->
// no scratch (R1 lesson). Uniform loop operands -> s_load_dwordx4.
// Output via ws + reduce (two-phase measured best: R5 70.7 vs R8 72.2).
__global__ __launch_bounds__(512, 8) void attn_sym2_kernel(
    const float* __restrict__ dec,   // [B, D]
    const float* __restrict__ enc,   // [B, T, D]
    float* __restrict__ ws) {        // [B*T, D] per-(b,t) contributions
    __shared__ float scs[2][DD];
    __shared__ float srs[2][DD];

    const int blk = blockIdx.x;              // b*TT + t
    const int b = blk >> 7;
    const int tid = threadIdx.x & (DD - 1);  // q
    const int h = threadIdx.x >> 8;          // 0..1: k-half

    const float* __restrict__ drow = dec + b * DD;    // uniform
    const float* __restrict__ erow = enc + blk * DD;  // uniform

    const float ev = erow[tid];              // per-lane, coalesced
    const float dl2 = drow[tid] * LOG2E;
    const float el2 = ev * LOG2E;

    float cs0 = 0.f, cs1 = 0.f, cs2 = 0.f, cs3 = 0.f;
    float rs0 = 0.f, rs1 = 0.f, rs2 = 0.f, rs3 = 0.f;
    const int k0 = h * (DD / 2);
    #pragma unroll 8
    for (int k = k0; k < k0 + DD / 2; k += 4) {
        float4 d4 = *reinterpret_cast<const float4*>(drow + k);  // s_load
        float4 e4 = *reinterpret_cast<const float4*>(erow + k);  // s_load
        cs0 += __builtin_amdgcn_exp2f(d4.x * el2);
        cs1 += __builtin_amdgcn_exp2f(d4.y * el2);
        cs2 += __builtin_amdgcn_exp2f(d4.z * el2);
        cs3 += __builtin_amdgcn_exp2f(d4.w * el2);
        rs0 += __builtin_amdgcn_exp2f(dl2 * e4.x);
        rs1 += __builtin_amdgcn_exp2f(dl2 * e4.y);
        rs2 += __builtin_amdgcn_exp2f(dl2 * e4.z);
        rs3 += __builtin_amdgcn_exp2f(dl2 * e4.w);
    }
    scs[h][tid] = (cs0 + cs1) + (cs2 + cs3);
    srs[h][tid] = (rs0 + rs1) + (rs2 + rs3);
    __syncthreads();

    if (h == 0) {
        const float cs = scs[0][tid] + scs[1][tid];
        const float rs = srs[0][tid] + srs[1][tid];
        ws[blk * DD + tid] = ev * cs / rs;
    }
}

// Phase 2: 32 blocks = (b, 64-wide q-slice). 256 threads = 4 t-chunks x 64 q.
__global__ __launch_bounds__(256) void reduce_t_kernel(
    const float* __restrict__ ws, float* __restrict__ out) {
    __shared__ float red[4][64];
    const int b = blockIdx.x >> 2;
    const int qc = blockIdx.x & 3;
    const int qlane = threadIdx.x & 63;
    const int tc = threadIdx.x >> 6;         // 0..3
    const int q = qc * 64 + qlane;

    const float* p = ws + (b * TT + tc * 32) * DD + q;
    float a0 = 0.f, a1 = 0.f, a2 = 0.f, a3 = 0.f;
    #pragma unroll
    for (int t = 0; t < 32; t += 4) {
        a0 += p[(t + 0) * DD];
        a1 += p[(t + 1) * DD];
        a2 += p[(t + 2) * DD];
        a3 += p[(t + 3) * DD];
    }
    red[tc][qlane] = (a0 + a1) + (a2 + a3);
    __syncthreads();
    if (tc == 0)
        out[b * DD + q] = red[0][qlane] + red[1][qlane] +
                          red[2][qlane] + red[3][qlane];
}

extern "C" void kernel_launch(void* const* d_in, const int* in_sizes, int n_in,
                              void* d_out, int out_size, void* d_ws, size_t ws_size,
                              hipStream_t stream) {
    const float* dec = (const float*)d_in[0];  // [B, D] fp32
    const float* enc = (const float*)d_in[1];  // [B, T, D] fp32
    float* out = (float*)d_out;                // [B, D] fp32
    float* ws = (float*)d_ws;                  // >= B*T*D floats

    attn_sym2_kernel<<<BB * TT, 512, 0, stream>>>(dec, enc, ws);
    reduce_t_kernel<<<BB * 4, 256, 0, stream>>>(ws, out);
}